// Round 11
// baseline (1228.758 us; speedup 1.0000x reference)
//
#include <hip/hip_runtime.h>

#define BB  1024
#define TT  1000
#define DD  6
#define HN  32
#define HHN 15

typedef _Float16 h2 __attribute__((ext_vector_type(2)));
typedef __fp16  fp16x2 __attribute__((ext_vector_type(2)));

__device__ __forceinline__ void pinf(float& v) { asm volatile("" : "+v"(v)); }
__device__ __forceinline__ void pinh(h2& v) {
    int t = __builtin_bit_cast(int, v);
    asm volatile("" : "+v"(t));
    v = __builtin_bit_cast(h2, t);
}

// RTN pack (setup only)
__device__ __forceinline__ h2 pkh_rtn(float a, float b) {
    h2 r; r.x = (_Float16)a; r.y = (_Float16)b; return r;
}
// fast pack (in-loop): v_cvt_pkrtz_f16_f32
__device__ __forceinline__ h2 pkh(float a, float b) {
    fp16x2 r = __builtin_amdgcn_cvt_pkrtz(a, b);
    return __builtin_bit_cast(h2, r);
}

#if defined(__has_builtin)
#if __has_builtin(__builtin_amdgcn_fdot2)
#define HAVE_FDOT2 1
#endif
#endif
// proven-correct dot2 (R8/R9): builtin emits proper VOP3P encoding
__device__ __forceinline__ float dot2(h2 a, h2 b, float c) {
#ifdef HAVE_FDOT2
    return __builtin_amdgcn_fdot2(a, b, c, false);
#else
    return fmaf((float)a.x, (float)b.x, fmaf((float)a.y, (float)b.y, c));
#endif
}

__device__ __forceinline__ h2 bch(h2 v, int l) {
    return __builtin_bit_cast(h2, __builtin_amdgcn_readlane(__builtin_bit_cast(int, v), l));
}
// validated DPP mappings (R8/R9 passed)
__device__ __forceinline__ float dpp_xor2(float v) {
    return __int_as_float(__builtin_amdgcn_update_dpp(0, __float_as_int(v), 0x4E, 0xF, 0xF, true));
}
__device__ __forceinline__ float dpp_shl4(float v) {
    return __int_as_float(__builtin_amdgcn_update_dpp(0, __float_as_int(v), 0x104, 0xF, 0xF, true));
}
__device__ __forceinline__ float dpp_xor1(float v) {
    return __int_as_float(__builtin_amdgcn_update_dpp(0, __float_as_int(v), 0xB1, 0xF, 0xF, true));
}

extern "C" __global__ void __launch_bounds__(64)
__attribute__((amdgpu_waves_per_eu(1, 1)))
cde_kernel(const float* __restrict__ coeffs,
           const float* __restrict__ W0, const float* __restrict__ b0,
           const float* __restrict__ W1, const float* __restrict__ b1,
           const float* __restrict__ W2, const float* __restrict__ b2,
           const float* __restrict__ W3, const float* __restrict__ b3,
           const float* __restrict__ W4, const float* __restrict__ b4,
           const float* __restrict__ Wf, const float* __restrict__ bf,
           float* __restrict__ out)
{
    const int b = blockIdx.x;
    const int L = threadIdx.x;               // one wave per block
    const float* cb = coeffs + (size_t)b * (TT * DD);

    const int quad = L >> 2;                 // neuron owned for layers 1-3
    const int iq   = (quad < HHN) ? quad : (HHN - 1);
    const int par  = L & 1;                  // layer-4 d-slot parity

    const float ELOG = 2.885390081777927f;   // 2*log2(e)

    // ---- persistent weights, f16-packed (RTN), pinned ----
    h2 w1p[16];
    #pragma unroll
    for (int m = 0; m < 16; ++m) {
        w1p[m] = pkh_rtn(W1[(2 * m) * HHN + iq], W1[(2 * m + 1) * HHN + iq]);
        pinh(w1p[m]);
    }
    h2 w2p[8], w3p[8];
    #pragma unroll
    for (int m = 0; m < 8; ++m) {
        float a2 = W2[(2 * m) * HHN + iq];
        float c2 = (2 * m + 1 < HHN) ? W2[(2 * m + 1) * HHN + iq] : 0.f;
        w2p[m] = pkh_rtn(a2, c2); pinh(w2p[m]);
        float a3 = W3[(2 * m) * HHN + iq];
        float c3 = (2 * m + 1 < HHN) ? W3[(2 * m + 1) * HHN + iq] : 0.f;
        w3p[m] = pkh_rtn(a3, c3); pinh(w3p[m]);
    }
    // quad 15 must produce z == 0 exactly (its slot is the hi half of pair 7)
    float bias1 = (quad < HHN) ? b1[iq] : -1e30f; pinf(bias1);
    float bias2 = (quad < HHN) ? b2[iq] : -1e30f; pinf(bias2);
    float bias3 = (quad < HHN) ? b3[iq] : -1e30f; pinf(bias3);

    // layer 4 pre-scaled by 2*log2e (exp2 needs no mul); lane owns cols c=3L+q
    h2 w4p[3][8]; float bias4s[3];
    #pragma unroll
    for (int q = 0; q < 3; ++q) {
        const int c = 3 * L + q;
        bias4s[q] = b4[c] * ELOG; pinf(bias4s[q]);
        #pragma unroll
        for (int m = 0; m < 8; ++m) {
            float a4 = W4[(2 * m) * (HN * DD) + c] * ELOG;
            float c4 = (2 * m + 1 < HHN) ? W4[(2 * m + 1) * (HN * DD) + c] * ELOG : 0.f;
            w4p[q][m] = pkh_rtn(a4, c4); pinh(w4p[q][m]);
        }
    }

    // ---- h distributed fp32: lane L holds h[L>>1] (pair-replicated) ----
    const int j = L >> 1;
    float hd = b0[j];
    #pragma unroll
    for (int d = 0; d < DD; ++d) hd = fmaf(cb[d], W0[d * HN + j], hd);

    // per-lane parity-swizzled x windows: even lanes see d=0..2, odd d=3..5
    float xAl[3], xBl[3];
    #pragma unroll
    for (int e = 0; e < 3; ++e) { xAl[e] = cb[par * 3 + e]; xBl[e] = cb[DD + par * 3 + e]; }

    h2 sy[16];          // wave-uniform packed y
    float m2d[3], sumdq;

    // distributed y (pair-replicated) -> 16 uniform packed words (R8 neck)
    auto uniy = [&](float yd) {
        const float yp = dpp_xor2(yd);       // lane 4m fetches y[2m+1] from 4m+2
        const h2 ypk = pkh(yd, yp);
        #pragma unroll
        for (int m = 0; m < 16; ++m) sy[m] = bch(ypk, 4 * m);
    };

    // one vector-field eval contracted with dx: sy -> g distributed (R9 internals)
    auto evalg = [&]() -> float {
        // layer 1: 16 dot2, 4 chains (bias folded)
        float a0 = bias1, a1 = 0.f, a2 = 0.f, a3 = 0.f;
        #pragma unroll
        for (int m = 0; m < 4; ++m) {
            a0 = dot2(sy[m],      w1p[m],      a0);
            a1 = dot2(sy[m + 4],  w1p[m + 4],  a1);
            a2 = dot2(sy[m + 8],  w1p[m + 8],  a2);
            a3 = dot2(sy[m + 12], w1p[m + 12], a3);
        }
        const float z1 = fmaxf((a0 + a1) + (a2 + a3), 0.f);
        h2 sz[8];
        {
            const float zp = dpp_shl4(z1);   // partner z from lane+4
            const h2 zpk = pkh(z1, zp);
            #pragma unroll
            for (int m = 0; m < 8; ++m) sz[m] = bch(zpk, 8 * m);
        }

        // layer 2: 8 dot2, 4 chains of 2
        float p0 = bias2, p1 = 0.f, p2 = 0.f, p3 = 0.f;
        p0 = dot2(sz[0], w2p[0], p0); p1 = dot2(sz[1], w2p[1], p1);
        p2 = dot2(sz[2], w2p[2], p2); p3 = dot2(sz[3], w2p[3], p3);
        p0 = dot2(sz[4], w2p[4], p0); p1 = dot2(sz[5], w2p[5], p1);
        p2 = dot2(sz[6], w2p[6], p2); p3 = dot2(sz[7], w2p[7], p3);
        const float z2 = fmaxf((p0 + p1) + (p2 + p3), 0.f);
        {
            const float zp = dpp_shl4(z2);
            const h2 zpk = pkh(z2, zp);
            #pragma unroll
            for (int m = 0; m < 8; ++m) sz[m] = bch(zpk, 8 * m);
        }

        // layer 3
        float q0 = bias3, q1 = 0.f, q2 = 0.f, q3 = 0.f;
        q0 = dot2(sz[0], w3p[0], q0); q1 = dot2(sz[1], w3p[1], q1);
        q2 = dot2(sz[2], w3p[2], q2); q3 = dot2(sz[3], w3p[3], q3);
        q0 = dot2(sz[4], w3p[4], q0); q1 = dot2(sz[5], w3p[5], q1);
        q2 = dot2(sz[6], w3p[6], q2); q3 = dot2(sz[7], w3p[7], q3);
        const float z3 = fmaxf((q0 + q1) + (q2 + q3), 0.f);
        {
            const float zp = dpp_shl4(z3);
            const h2 zpk = pkh(z3, zp);
            #pragma unroll
            for (int m = 0; m < 8; ++m) sz[m] = bch(zpk, 8 * m);
        }

        // layer 4 (pre-scaled): 3 cols, 2 chains of 4 each
        float s[3];
        #pragma unroll
        for (int q = 0; q < 3; ++q) {
            float s0 = bias4s[q], s1 = 0.f;
            s0 = dot2(sz[0], w4p[q][0], s0); s1 = dot2(sz[4], w4p[q][4], s1);
            s0 = dot2(sz[1], w4p[q][1], s0); s1 = dot2(sz[5], w4p[q][5], s1);
            s0 = dot2(sz[2], w4p[q][2], s0); s1 = dot2(sz[6], w4p[q][6], s1);
            s0 = dot2(sz[3], w4p[q][3], s0); s1 = dot2(sz[7], w4p[q][7], s1);
            s[q] = s0 + s1;
        }
        // sum_q dq*tanh = sumdq + sum_q (-2 dq) * rcp(exp2(s') + 1)
        float partial = sumdq;
        #pragma unroll
        for (int q = 0; q < 3; ++q) {
            const float e = __builtin_amdgcn_exp2f(s[q]);
            const float r = __builtin_amdgcn_rcpf(e + 1.0f);
            partial = fmaf(m2d[q], r, partial);
        }
        // g[j] = partial(2j) + partial(2j+1); both lanes of the pair get it
        return partial + dpp_xor1(partial);
    };

    #pragma unroll 1
    for (int t = 0; t < TT - 1; ++t) {
        float dxl[3];
        #pragma unroll
        for (int e = 0; e < 3; ++e) dxl[e] = xBl[e] - xAl[e];
        sumdq = (dxl[0] + dxl[1]) + dxl[2];
        #pragma unroll
        for (int e = 0; e < 3; ++e) m2d[e] = -2.0f * dxl[e];

        // prefetch x[t+2] from global (L2-resident; ~2 steps of slack)
        const int tn = (t + 2 < TT) ? (t + 2) : (TT - 1);
        float xNl[3];
        #pragma unroll
        for (int e = 0; e < 3; ++e) xNl[e] = cb[tn * DD + par * 3 + e];

        uniy(hd);
        const float g1 = evalg();
        float acc = g1;
        uniy(fmaf(0.5f, g1, hd));
        const float g2 = evalg();
        acc = fmaf(2.f, g2, acc);
        uniy(fmaf(0.5f, g2, hd));
        const float g3 = evalg();
        acc = fmaf(2.f, g3, acc);
        uniy(hd + g3);
        const float g4 = evalg();
        hd = fmaf(1.f / 6.f, acc + g4, hd);

        #pragma unroll
        for (int e = 0; e < 3; ++e) { xAl[e] = xBl[e]; xBl[e] = xNl[e]; }
    }

    // ---- out[b] = h . Wf + bf (each h[j] appears on 2 lanes -> *0.5) ----
    float pz = hd * Wf[j] * 0.5f;
    #pragma unroll
    for (int off = 32; off > 0; off >>= 1) pz += __shfl_xor(pz, off);
    if (L == 0) out[b] = pz + bf[0];
}

extern "C" void kernel_launch(void* const* d_in, const int* in_sizes, int n_in,
                              void* d_out, int out_size, void* d_ws, size_t ws_size,
                              hipStream_t stream) {
    const float* coeffs = (const float*)d_in[0];
    const float* W0 = (const float*)d_in[1];
    const float* b0 = (const float*)d_in[2];
    const float* W1 = (const float*)d_in[3];
    const float* b1 = (const float*)d_in[4];
    const float* W2 = (const float*)d_in[5];
    const float* b2 = (const float*)d_in[6];
    const float* W3 = (const float*)d_in[7];
    const float* b3 = (const float*)d_in[8];
    const float* W4 = (const float*)d_in[9];
    const float* b4 = (const float*)d_in[10];
    const float* Wf = (const float*)d_in[11];
    const float* bf = (const float*)d_in[12];
    float* out = (float*)d_out;

    hipLaunchKernelGGL(cde_kernel, dim3(BB), dim3(64), 0, stream,
                       coeffs, W0, b0, W1, b1, W2, b2, W3, b3, W4, b4, Wf, bf, out);
}

// Round 12
// 1203.596 us; speedup vs baseline: 1.0209x; 1.0209x over previous
//
#include <hip/hip_runtime.h>

#define BB  1024
#define TT  1000
#define DD  6
#define HN  32
#define HHN 15

typedef _Float16 h2 __attribute__((ext_vector_type(2)));
typedef __fp16  fp16x2 __attribute__((ext_vector_type(2)));

__device__ __forceinline__ void pinf(float& v) { asm volatile("" : "+v"(v)); }
__device__ __forceinline__ void pinh(h2& v) {
    int t = __builtin_bit_cast(int, v);
    asm volatile("" : "+v"(t));
    v = __builtin_bit_cast(h2, t);
}

// RTN pack (setup only)
__device__ __forceinline__ h2 pkh_rtn(float a, float b) {
    h2 r; r.x = (_Float16)a; r.y = (_Float16)b; return r;
}
// fast pack (in-loop): v_cvt_pkrtz_f16_f32
__device__ __forceinline__ h2 pkh(float a, float b) {
    fp16x2 r = __builtin_amdgcn_cvt_pkrtz(a, b);
    return __builtin_bit_cast(h2, r);
}

#if defined(__has_builtin)
#if __has_builtin(__builtin_amdgcn_fdot2)
#define HAVE_FDOT2 1
#endif
#endif
__device__ __forceinline__ float dot2(h2 a, h2 b, float c) {
#ifdef HAVE_FDOT2
    return __builtin_amdgcn_fdot2(a, b, c, false);
#else
    return fmaf((float)a.x, (float)b.x, fmaf((float)a.y, (float)b.y, c));
#endif
}

__device__ __forceinline__ h2 bch(h2 v, int l) {
    return __builtin_bit_cast(h2, __builtin_amdgcn_readlane(__builtin_bit_cast(int, v), l));
}
// DPP: fetch lane^2 within quad (quad_perm [2,3,0,1])
__device__ __forceinline__ float dpp_xor2(float v) {
    return __int_as_float(__builtin_amdgcn_update_dpp(0, __float_as_int(v), 0x4E, 0xF, 0xF, true));
}
// DPP: fetch lane+4 within 16-lane row (row_shl:4 = 0x104)
__device__ __forceinline__ float dpp_shl4(float v) {
    return __int_as_float(__builtin_amdgcn_update_dpp(0, __float_as_int(v), 0x104, 0xF, 0xF, true));
}
// add lane^1 partner (quad_perm [1,0,3,2])
__device__ __forceinline__ float qadd1(float v) {
    int t = __builtin_amdgcn_update_dpp(0, __float_as_int(v), 0xB1, 0xF, 0xF, true);
    return v + __int_as_float(t);
}
// tanh(x) = 1 - 2/(exp2(2*log2e*x)+1); exact saturation, rel err ~1e-6
__device__ __forceinline__ float tanh_fast(float x) {
    float e = __builtin_amdgcn_exp2f(x * 2.885390081777927f);
    return fmaf(-2.0f, __builtin_amdgcn_rcpf(e + 1.0f), 1.0f);
}

extern "C" __global__ void __launch_bounds__(64)
__attribute__((amdgpu_waves_per_eu(1, 1)))
cde_kernel(const float* __restrict__ coeffs,
           const float* __restrict__ W0, const float* __restrict__ b0,
           const float* __restrict__ W1, const float* __restrict__ b1,
           const float* __restrict__ W2, const float* __restrict__ b2,
           const float* __restrict__ W3, const float* __restrict__ b3,
           const float* __restrict__ W4, const float* __restrict__ b4,
           const float* __restrict__ Wf, const float* __restrict__ bf,
           float* __restrict__ out)
{
    const int b = blockIdx.x;
    const int L = threadIdx.x;               // one wave per block
    const float* cb = coeffs + (size_t)b * (TT * DD);

    const int quad = L >> 2;                 // neuron owned for layers 1-3
    const int iq   = (quad < HHN) ? quad : (HHN - 1);
    const int par  = L & 1;                  // layer-4 d-slot parity

    // ---- persistent weights, f16-packed (RTN), pinned ----
    h2 w1p[16];
    #pragma unroll
    for (int m = 0; m < 16; ++m) {
        w1p[m] = pkh_rtn(W1[(2 * m) * HHN + iq], W1[(2 * m + 1) * HHN + iq]);
        pinh(w1p[m]);
    }
    h2 w2p[8], w3p[8];
    #pragma unroll
    for (int m = 0; m < 8; ++m) {
        float a2 = W2[(2 * m) * HHN + iq];
        float c2 = (2 * m + 1 < HHN) ? W2[(2 * m + 1) * HHN + iq] : 0.f;
        w2p[m] = pkh_rtn(a2, c2); pinh(w2p[m]);
        float a3 = W3[(2 * m) * HHN + iq];
        float c3 = (2 * m + 1 < HHN) ? W3[(2 * m + 1) * HHN + iq] : 0.f;
        w3p[m] = pkh_rtn(a3, c3); pinh(w3p[m]);
    }
    // quad 15 must produce z == 0 exactly (its slot is the hi half of pair 7)
    float bias1 = (quad < HHN) ? b1[iq] : -1e30f; pinf(bias1);
    float bias2 = (quad < HHN) ? b2[iq] : -1e30f; pinf(bias2);
    float bias3 = (quad < HHN) ? b3[iq] : -1e30f; pinf(bias3);

    // layer 4: lane owns cols c = 3L+q; lanes (2j,2j+1) together cover h-index j
    h2 w4p[3][8]; float bias4[3];
    #pragma unroll
    for (int q = 0; q < 3; ++q) {
        const int c = 3 * L + q;
        bias4[q] = b4[c]; pinf(bias4[q]);
        #pragma unroll
        for (int m = 0; m < 8; ++m) {
            float a4 = W4[(2 * m) * (HN * DD) + c];
            float c4 = (2 * m + 1 < HHN) ? W4[(2 * m + 1) * (HN * DD) + c] : 0.f;
            w4p[q][m] = pkh_rtn(a4, c4); pinh(w4p[q][m]);
        }
    }

    // ---- h distributed fp32: lane L holds h[L>>1] (pair-replicated) ----
    const int j = L >> 1;
    float hd = b0[j];
    #pragma unroll
    for (int d = 0; d < DD; ++d) hd = fmaf(cb[d], W0[d * HN + j], hd);

    // per-lane parity-swizzled x windows: even lanes see d=0..2, odd d=3..5
    float xAl[3], xBl[3];
    #pragma unroll
    for (int e = 0; e < 3; ++e) { xAl[e] = cb[par * 3 + e]; xBl[e] = cb[DD + par * 3 + e]; }

    h2 sy[16];          // wave-uniform packed y
    float dxl[3];

    // distributed y (pair-replicated) -> 16 uniform packed SGPRs
    auto uniy = [&](float yd) {
        const float yp = dpp_xor2(yd);       // lane 4m fetches y[2m+1] from 4m+2
        const h2 ypk = pkh(yd, yp);
        #pragma unroll
        for (int m = 0; m < 16; ++m) sy[m] = bch(ypk, 4 * m);
    };

    // one vector-field eval contracted with dx: sy -> g distributed
    auto evalg = [&]() -> float {
        // layer 1: 16 dot2, 4 chains (bias folded)
        float a0 = bias1, a1 = 0.f, a2 = 0.f, a3 = 0.f;
        #pragma unroll
        for (int m = 0; m < 4; ++m) {
            a0 = dot2(sy[m],      w1p[m],      a0);
            a1 = dot2(sy[m + 4],  w1p[m + 4],  a1);
            a2 = dot2(sy[m + 8],  w1p[m + 8],  a2);
            a3 = dot2(sy[m + 12], w1p[m + 12], a3);
        }
        const float z1 = fmaxf((a0 + a1) + (a2 + a3), 0.f);
        h2 sz[8];
        {
            const float zp = dpp_shl4(z1);   // partner z from lane+4
            const h2 zpk = pkh(z1, zp);
            #pragma unroll
            for (int m = 0; m < 8; ++m) sz[m] = bch(zpk, 8 * m);
        }

        // layer 2: 8 dot2, 2 chains
        float p0 = bias2, p1 = 0.f;
        p0 = dot2(sz[0], w2p[0], p0); p1 = dot2(sz[1], w2p[1], p1);
        p0 = dot2(sz[2], w2p[2], p0); p1 = dot2(sz[3], w2p[3], p1);
        p0 = dot2(sz[4], w2p[4], p0); p1 = dot2(sz[5], w2p[5], p1);
        p0 = dot2(sz[6], w2p[6], p0); p1 = dot2(sz[7], w2p[7], p1);
        const float z2 = fmaxf(p0 + p1, 0.f);
        {
            const float zp = dpp_shl4(z2);
            const h2 zpk = pkh(z2, zp);
            #pragma unroll
            for (int m = 0; m < 8; ++m) sz[m] = bch(zpk, 8 * m);
        }

        // layer 3
        float q0 = bias3, q1 = 0.f;
        q0 = dot2(sz[0], w3p[0], q0); q1 = dot2(sz[1], w3p[1], q1);
        q0 = dot2(sz[2], w3p[2], q0); q1 = dot2(sz[3], w3p[3], q1);
        q0 = dot2(sz[4], w3p[4], q0); q1 = dot2(sz[5], w3p[5], q1);
        q0 = dot2(sz[6], w3p[6], q0); q1 = dot2(sz[7], w3p[7], q1);
        const float z3 = fmaxf(q0 + q1, 0.f);
        {
            const float zp = dpp_shl4(z3);
            const h2 zpk = pkh(z3, zp);
            #pragma unroll
            for (int m = 0; m < 8; ++m) sz[m] = bch(zpk, 8 * m);
        }

        // layer 4 + tanh + dot(dx): 3 cols per lane, 2 chains of 4 each
        float s0[3], s1[3];
        #pragma unroll
        for (int q = 0; q < 3; ++q) {
            s0[q] = bias4[q]; s1[q] = 0.f;
            s0[q] = dot2(sz[0], w4p[q][0], s0[q]); s1[q] = dot2(sz[4], w4p[q][4], s1[q]);
            s0[q] = dot2(sz[1], w4p[q][1], s0[q]); s1[q] = dot2(sz[5], w4p[q][5], s1[q]);
            s0[q] = dot2(sz[2], w4p[q][2], s0[q]); s1[q] = dot2(sz[6], w4p[q][6], s1[q]);
            s0[q] = dot2(sz[3], w4p[q][3], s0[q]); s1[q] = dot2(sz[7], w4p[q][7], s1[q]);
        }
        float partial = 0.f;
        #pragma unroll
        for (int q = 0; q < 3; ++q)
            partial = fmaf(tanh_fast(s0[q] + s1[q]), dxl[q], partial);
        // g[j] = partial(2j) + partial(2j+1); both lanes of the pair get it
        return qadd1(partial);
    };

    #pragma unroll 1
    for (int t = 0; t < TT - 1; ++t) {
        #pragma unroll
        for (int e = 0; e < 3; ++e) dxl[e] = xBl[e] - xAl[e];

        // prefetch x[t+2] from global (L2-resident; ~2 steps of slack)
        const int tn = (t + 2 < TT) ? (t + 2) : (TT - 1);
        float xNl[3];
        #pragma unroll
        for (int e = 0; e < 3; ++e) xNl[e] = cb[tn * DD + par * 3 + e];

        uniy(hd);
        const float g1 = evalg();
        float acc = g1;
        uniy(fmaf(0.5f, g1, hd));
        const float g2 = evalg();
        acc = fmaf(2.f, g2, acc);
        uniy(fmaf(0.5f, g2, hd));
        const float g3 = evalg();
        acc = fmaf(2.f, g3, acc);
        uniy(hd + g3);
        const float g4 = evalg();
        hd = fmaf(1.f / 6.f, acc + g4, hd);

        #pragma unroll
        for (int e = 0; e < 3; ++e) { xAl[e] = xBl[e]; xBl[e] = xNl[e]; }
    }

    // ---- out[b] = h . Wf + bf (each h[j] appears on 2 lanes -> *0.5) ----
    float pz = hd * Wf[j] * 0.5f;
    #pragma unroll
    for (int off = 32; off > 0; off >>= 1) pz += __shfl_xor(pz, off);
    if (L == 0) out[b] = pz + bf[0];
}

extern "C" void kernel_launch(void* const* d_in, const int* in_sizes, int n_in,
                              void* d_out, int out_size, void* d_ws, size_t ws_size,
                              hipStream_t stream) {
    const float* coeffs = (const float*)d_in[0];
    const float* W0 = (const float*)d_in[1];
    const float* b0 = (const float*)d_in[2];
    const float* W1 = (const float*)d_in[3];
    const float* b1 = (const float*)d_in[4];
    const float* W2 = (const float*)d_in[5];
    const float* b2 = (const float*)d_in[6];
    const float* W3 = (const float*)d_in[7];
    const float* b3 = (const float*)d_in[8];
    const float* W4 = (const float*)d_in[9];
    const float* b4 = (const float*)d_in[10];
    const float* Wf = (const float*)d_in[11];
    const float* bf = (const float*)d_in[12];
    float* out = (float*)d_out;

    hipLaunchKernelGGL(cde_kernel, dim3(BB), dim3(64), 0, stream,
                       coeffs, W0, b0, W1, b1, W2, b2, W3, b3, W4, b4, Wf, bf, out);
}